// Round 5
// baseline (93.260 us; speedup 1.0000x reference)
//
#include <hip/hip_runtime.h>
#include <math.h>

#define NQ    13
#define DIM   8192
#define BLOCK 512
#define NGATE 26

typedef float v2f __attribute__((ext_vector_type(2)));

// Swizzle on LDS *word* address: xor bits[4:2] with bits[9:7].
// Preserves bits[1:0] -> b128/b64 alignment intact; balances bank quads
// (verified per-pass: every b128 op lands 8 lanes on each of 8 bank-quads).
__device__ __forceinline__ int SW(int a) { return a ^ (((a >> 7) & 7) << 2); }

// ---- CNOT-chain permutation (GF(2)-linear), compile-time ----
struct PCols { int c[NQ]; };
constexpr PCols make_cols(int r) {
    PCols P{};
    for (int b = 0; b < NQ; ++b) {
        int cc = 1 << b;
        for (int cq = 0; cq < NQ; ++cq) {
            const int cb = 12 - cq;
            const int tb = 12 - ((cq + r) % NQ);
            cc ^= ((cc >> cb) & 1) << tb;
        }
        P.c[b] = cc;
    }
    return P;
}
constexpr PCols C1c = make_cols(1);  // layer 0 (r=1)
constexpr int make_rm6() {           // row 6 of layer-1 (r=2) permutation
    int m = 0;
    for (int b = 0; b < NQ; ++b) m |= ((make_cols(2).c[b] >> 6) & 1) << b;
    return m;
}
constexpr int RM6 = make_rm6();

// Pass-2 reg-bit scatter combos: j0->i0, j1->i8, j2->i9, j3->i10
struct Combos { int k[16]; };
constexpr Combos make_combos() {
    Combos K{};
    for (int j = 0; j < 16; ++j)
        K.k[j] = ((j & 1) ? C1c.c[0] : 0) ^ ((j & 2) ? C1c.c[8] : 0)
               ^ ((j & 4) ? C1c.c[9] : 0) ^ ((j & 8) ? C1c.c[10] : 0);
    return K;
}
constexpr Combos KC = make_combos();

// Per-j PauliZ parity for the final reduce (j bits -> i bits {0,8,9,10})
constexpr int make_sjw() {
    int wv = 0;
    for (int j = 0; j < 16; ++j) {
        const int jm = (j & 1) | (((j >> 1) & 7) << 8);
        wv |= (__builtin_popcount(jm & RM6) & 1) << j;
    }
    return wv;
}
constexpr int SJW = make_sjw();

struct GPair { float4 a, b; };  // u00,u01 | u10,u11 (re,im interleaved)
__device__ __forceinline__ GPair ldg8(const float* gm, int gi) {
    GPair g;
    g.a = *(const float4*)&gm[gi * 8];
    g.b = *(const float4*)&gm[gi * 8 + 4];
    return g;
}

// Rot gate on 16-amp register subcube, pair bit = reg bit P
template<int P>
__device__ __forceinline__ void rotp(v2f* c, const GPair g) {
    #pragma unroll
    for (int m = 0; m < 8; ++m) {
        const int j0 = ((m >> P) << (P + 1)) | (m & ((1 << P) - 1));
        const int j1 = j0 | (1 << P);
        const v2f a0 = c[j0], a1 = c[j1];
        const v2f s0 = { -a0.y, a0.x };
        const v2f s1 = { -a1.y, a1.x };
        c[j0] = g.a.x * a0 + g.a.y * s0 + g.a.z * a1 + g.a.w * s1;
        c[j1] = g.b.x * a0 + g.b.y * s0 + g.b.z * a1 + g.b.w * s1;
    }
}

// DPP lane exchanges. xor1=quad[1,0,3,2]; xor2=quad[2,3,0,1];
// xor4 = half_mirror(^7) then quad[3,2,1,0](^3); xor8 = mirror(^15) then half_mirror(^7).
#define DPP_XOR1 0xB1
#define DPP_XOR2 0x4E
#define DPP_QREV 0x1B
#define DPP_HMIR 0x141
#define DPP_MIR  0x140

template<int CTRL>
__device__ __forceinline__ float dpp1(float v) {
    return __int_as_float(
        __builtin_amdgcn_update_dpp(0, __float_as_int(v), CTRL, 0xf, 0xf, true));
}
template<int CA, int CB>
__device__ __forceinline__ float dppx(float v) {
    float r = dpp1<CA>(v);
    if constexpr (CB >= 0) r = dpp1<CB>(r);
    return r;
}

// Rot gate with the pair bit in a lane bit.
template<int CA, int CB>
__device__ __forceinline__ void rotlane(v2f* c, const GPair g, const bool hi) {
    const float Ar = hi ? g.b.z : g.a.x;
    const float Ai = hi ? g.b.w : g.a.y;
    const float Br = hi ? g.b.x : g.a.z;
    const float Bi = hi ? g.b.y : g.a.w;
    #pragma unroll
    for (int j = 0; j < 16; ++j) {
        v2f p;
        p.x = dppx<CA, CB>(c[j].x);
        p.y = dppx<CA, CB>(c[j].y);
        const v2f so = { -c[j].y, c[j].x };
        const v2f sp = { -p.y, p.x };
        c[j] = Ar * c[j] + Ai * so + Br * p + Bi * sp;
    }
}

// Pass-layout address helpers (word addresses, pre-swizzle):
//  P1: i = t<<4 | j  -> group g (j=2g,2g+1) at words (t<<5)|(g<<2)
//  P2: i = j0 | t[8:2]<<1 | j[3:1]<<8 | t[1:0]<<11
//      -> group g at words t[8:2]<<2 | g<<9 | t[1:0]<<12
__device__ __forceinline__ void p1_load(const float* st, int t, v2f* c) {
    #pragma unroll
    for (int g = 0; g < 8; ++g) {
        const float4 v = *(const float4*)&st[SW((t << 5) | (g << 2))];
        c[2 * g]     = { v.x, v.y };
        c[2 * g + 1] = { v.z, v.w };
    }
}
__device__ __forceinline__ void p1_store(float* st, int t, const v2f* c) {
    #pragma unroll
    for (int g = 0; g < 8; ++g) {
        const float4 v = { c[2 * g].x, c[2 * g].y, c[2 * g + 1].x, c[2 * g + 1].y };
        *(float4*)&st[SW((t << 5) | (g << 2))] = v;
    }
}
__device__ __forceinline__ void p2_load(const float* st, int base, v2f* c) {
    #pragma unroll
    for (int g = 0; g < 8; ++g) {
        const float4 v = *(const float4*)&st[SW(base | (g << 9))];
        c[2 * g]     = { v.x, v.y };
        c[2 * g + 1] = { v.z, v.w };
    }
}

__global__ __launch_bounds__(BLOCK, 4) void qsim_kernel(
    const float* __restrict__ x,
    const float* __restrict__ w,
    float* __restrict__ out)
{
    __shared__ __align__(16) float st[2 * DIM];   // interleaved (re,im), swizzled
    __shared__ __align__(16) float gm[NGATE * 8];
    __shared__ float red_ss[8], red_acc[8];

    const int b = blockIdx.x;
    const int t = threadIdx.x;

    // ---- gate matrices, 26 threads, once per block ----
    if (t < NGATE) {
        const float phi = w[t * 3 + 0], theta = w[t * 3 + 1], omega = w[t * 3 + 2];
        float co, si;  sincosf(0.5f * theta, &si, &co);
        float sps, cps, sds, cds;
        sincosf(0.5f * (phi + omega), &sps, &cps);
        sincosf(0.5f * (phi - omega), &sds, &cds);
        float* g = &gm[t * 8];
        g[0] =  cps * co;  g[1] = -sps * co;   // u00
        g[2] = -cds * si;  g[3] = -sds * si;   // u01
        g[4] =  cds * si;  g[5] = -sds * si;   // u10
        g[6] =  cps * co;  g[7] =  sps * co;   // u11
    }

    // ---- L0-P1: global -> registers directly (i = t<<4 | j), ss on the fly ----
    const float4* x4 = (const float4*)(x + (size_t)b * DIM);
    v2f c[16];
    float ss = 0.f;
    #pragma unroll
    for (int k = 0; k < 4; ++k) {
        const float4 v = x4[(t << 2) | k];
        c[4 * k + 0] = { v.x, 0.f };
        c[4 * k + 1] = { v.y, 0.f };
        c[4 * k + 2] = { v.z, 0.f };
        c[4 * k + 3] = { v.w, 0.f };
        ss += v.x * v.x + v.y * v.y + v.z * v.z + v.w * v.w;
    }
    #pragma unroll
    for (int off = 32; off > 0; off >>= 1) ss += __shfl_down(ss, off, 64);
    if ((t & 63) == 0) red_ss[t >> 6] = ss;
    __syncthreads();                           // B1: gm (and red_ss) visible

    const int p2base = (((t >> 2) & 127) << 2) | ((t & 3) << 12);

    // ================= layer 0 =================
    // P1 gates: q12..q9 (reg), q8,q7,q6,q5 (lane xor1,2,4,8)
    rotp<0>(c, ldg8(gm, 12));
    rotp<1>(c, ldg8(gm, 11));
    rotp<2>(c, ldg8(gm, 10));
    rotp<3>(c, ldg8(gm,  9));
    rotlane<DPP_XOR1, -1>(c, ldg8(gm, 8), (t & 1) != 0);
    rotlane<DPP_XOR2, -1>(c, ldg8(gm, 7), (t & 2) != 0);
    rotlane<DPP_HMIR, DPP_QREV>(c, ldg8(gm, 6), (t & 4) != 0);
    rotlane<DPP_MIR,  DPP_HMIR>(c, ldg8(gm, 5), (t & 8) != 0);
    p1_store(st, t, c);
    __syncthreads();                           // B2

    // P2 gates: q4,q3,q2 (reg j1,j2,j3), q1,q0 (lane xor1,xor2)
    p2_load(st, p2base, c);
    rotp<1>(c, ldg8(gm, 4));
    rotp<2>(c, ldg8(gm, 3));
    rotp<3>(c, ldg8(gm, 2));
    rotlane<DPP_XOR1, -1>(c, ldg8(gm, 1), (t & 1) != 0);
    rotlane<DPP_XOR2, -1>(c, ldg8(gm, 0), (t & 2) != 0);
    __syncthreads();                           // B3: all reads done pre-scatter

    // All 13 layer-0 CNOTs as one GF(2)-linear scatter (b64 complex stores)
    {
        int mb = 0;
        #pragma unroll
        for (int k = 0; k < 7; ++k)            // i[7:1] = t[8:2]
            if ((t >> (2 + k)) & 1) mb ^= C1c.c[1 + k];
        if (t & 1) mb ^= C1c.c[11];            // i11 = t0
        if (t & 2) mb ^= C1c.c[12];            // i12 = t1
        #pragma unroll
        for (int j = 0; j < 16; ++j) {
            const int a = SW(2 * (mb ^ KC.k[j]));
            *(v2f*)&st[a] = c[j];
        }
    }
    __syncthreads();                           // B4

    // ================= layer 1 =================
    p1_load(st, t, c);
    rotp<0>(c, ldg8(gm, 13 + 12));
    rotp<1>(c, ldg8(gm, 13 + 11));
    rotp<2>(c, ldg8(gm, 13 + 10));
    rotp<3>(c, ldg8(gm, 13 +  9));
    rotlane<DPP_XOR1, -1>(c, ldg8(gm, 13 + 8), (t & 1) != 0);
    rotlane<DPP_XOR2, -1>(c, ldg8(gm, 13 + 7), (t & 2) != 0);
    rotlane<DPP_HMIR, DPP_QREV>(c, ldg8(gm, 13 + 6), (t & 4) != 0);
    rotlane<DPP_MIR,  DPP_HMIR>(c, ldg8(gm, 13 + 5), (t & 8) != 0);
    p1_store(st, t, c);
    __syncthreads();                           // B5

    p2_load(st, p2base, c);
    rotp<1>(c, ldg8(gm, 13 + 4));
    rotp<2>(c, ldg8(gm, 13 + 3));
    rotp<3>(c, ldg8(gm, 13 + 2));
    rotlane<DPP_XOR1, -1>(c, ldg8(gm, 13 + 1), (t & 1) != 0);
    rotlane<DPP_XOR2, -1>(c, ldg8(gm, 13 + 0), (t & 2) != 0);

    // ---- layer-1 CNOTs + PauliZ(q6) folded: sign = popc(C2(i) bit6) ----
    const int fixed = ((((t >> 2) & 127) << 1) | ((t & 3) << 11));
    const int sbase = __popc(fixed & RM6) & 1;
    float acc = 0.f;
    #pragma unroll
    for (int j = 0; j < 16; ++j) {
        const float p = c[j].x * c[j].x + c[j].y * c[j].y;
        acc += (sbase ^ ((SJW >> j) & 1)) ? -p : p;
    }
    #pragma unroll
    for (int off = 32; off > 0; off >>= 1) acc += __shfl_down(acc, off, 64);
    if ((t & 63) == 0) red_acc[t >> 6] = acc;
    __syncthreads();                           // B6
    if (t == 0) {
        float ta = 0.f, ts = 0.f;
        #pragma unroll
        for (int i = 0; i < 8; ++i) { ta += red_acc[i]; ts += red_ss[i]; }
        out[b] = ta / ts;
    }
}

extern "C" void kernel_launch(void* const* d_in, const int* in_sizes, int n_in,
                              void* d_out, int out_size, void* d_ws, size_t ws_size,
                              hipStream_t stream) {
    const float* x = (const float*)d_in[0];   // (512, 8192) fp32
    const float* w = (const float*)d_in[1];   // (2, 13, 3) fp32
    float* out = (float*)d_out;               // (512,) fp32
    const int B = in_sizes[0] / DIM;
    qsim_kernel<<<B, BLOCK, 0, stream>>>(x, w, out);
}

// Round 7
// 84.389 us; speedup vs baseline: 1.1051x; 1.1051x over previous
//
#include <hip/hip_runtime.h>
#include <math.h>

#define NQ    13
#define DIM   8192
#define BLOCK 512
#define NGATE 26

// R7 = R4 proven skeleton (85.4 us, passed) + three local edits:
//  (1) layer-0 im elision (state starts real): P0 stages re only; layer-0
//      pass-1 sets im=0 in registers.
//  (2) gate-matrix broadcast reads as 2x b128 (G8) instead of 8x b32.
//  (3) pass-3 read-drain barrier only on layer 0 (layer 1 has no scatter).
// All bit maps, swizzle, and barriers otherwise identical to R4.

// Bank-quad spreading swizzle: XOR addr[4:2] with addr[9:7]. Preserves
// addr[1:0] => b128 groups stay intact. Applied at every LDS access.
__device__ __forceinline__ int SW(int a) { return a ^ (((a >> 7) & 7) << 2); }

// ---- CNOT-chain permutation (GF(2)-linear), compile-time ----
struct PCols { int c[NQ]; };
constexpr PCols make_cols(int r) {
    PCols P{};
    for (int b = 0; b < NQ; ++b) {
        int cc = 1 << b;
        for (int cq = 0; cq < NQ; ++cq) {
            const int cb = 12 - cq;
            const int tb = 12 - ((cq + r) % NQ);
            cc ^= ((cc >> cb) & 1) << tb;
        }
        P.c[b] = cc;
    }
    return P;
}
constexpr PCols C1 = make_cols(1);   // layer 0 CNOTs (r=1)
constexpr int make_rm6() {           // row 6 of layer-1 (r=2) permutation matrix
    int m = 0;
    for (int b = 0; b < NQ; ++b) m |= ((make_cols(2).c[b] >> 6) & 1) << b;
    return m;
}
constexpr int RM6 = make_rm6();

// scatter combos for pass-3 reg bits: j0->i0, j1->i1, j2->i10, j3->i11
struct Combos { int k[16]; };
constexpr Combos make_combos() {
    Combos K{};
    for (int j = 0; j < 16; ++j)
        K.k[j] = ((j & 1) ? C1.c[0] : 0) ^ ((j & 2) ? C1.c[1] : 0)
               ^ ((j & 4) ? C1.c[10] : 0) ^ ((j & 8) ? C1.c[11] : 0);
    return K;
}
constexpr Combos KC = make_combos();

// per-j PauliZ sign parity for the final reduce (j bits -> i bits {0,1,10,11})
constexpr int make_sjw() {
    int wv = 0;
    for (int j = 0; j < 16; ++j) {
        const int jm = (j & 3) | (((j >> 2) & 3) << 10);
        wv |= (__builtin_popcount(jm & RM6) & 1) << j;
    }
    return wv;
}
constexpr int SJW = make_sjw();

// ---- float2 complex helpers ----
__device__ __forceinline__ float2 f2mul(float s, float2 a) {
    return make_float2(s * a.x, s * a.y);
}
__device__ __forceinline__ float2 f2fma(float s, float2 a, float2 b) {
    return make_float2(fmaf(s, a.x, b.x), fmaf(s, a.y, b.y));
}
__device__ __forceinline__ float2 fswap(float2 a) { return make_float2(-a.y, a.x); }

// gate matrix as two float4 broadcasts:
//   a = {u00r,u00i,u01r,u01i}, b = {u10r,u10i,u11r,u11i}
struct G8 { float4 a, b; };
__device__ __forceinline__ G8 ldg8(const float* gm, int gi) {
    G8 g;
    g.a = *(const float4*)&gm[gi * 8];
    g.b = *(const float4*)&gm[gi * 8 + 4];
    return g;
}

// Rot gate on 16-amp register subcube, pair bit = reg index bit P
template<int P>
__device__ __forceinline__ void rotp(float2* c, const G8 g) {
    #pragma unroll
    for (int m = 0; m < 8; ++m) {
        const int j0 = ((m >> P) << (P + 1)) | (m & ((1 << P) - 1));
        const int j1 = j0 | (1 << P);
        const float2 a0 = c[j0], a1 = c[j1];
        const float2 s0 = fswap(a0), s1 = fswap(a1);
        c[j0] = f2fma(g.a.w, s1, f2fma(g.a.z, a1, f2fma(g.a.y, s0, f2mul(g.a.x, a0))));
        c[j1] = f2fma(g.b.w, s1, f2fma(g.b.z, a1, f2fma(g.b.y, s0, f2mul(g.b.x, a0))));
    }
}

// DPP quad-perm lane exchange: 0xB1 -> lane^1, 0x4E -> lane^2
template<int CTRL>
__device__ __forceinline__ float dppx(float v) {
    return __int_as_float(
        __builtin_amdgcn_update_dpp(0, __float_as_int(v), CTRL, 0xf, 0xf, true));
}
template<int CTRL>
__device__ __forceinline__ void rotlane(float2* c, const G8 g, const bool hi) {
    const float Ar = hi ? g.b.z : g.a.x;
    const float Ai = hi ? g.b.w : g.a.y;
    const float Br = hi ? g.b.x : g.a.z;
    const float Bi = hi ? g.b.y : g.a.w;
    #pragma unroll
    for (int j = 0; j < 16; ++j) {
        const float2 p  = make_float2(dppx<CTRL>(c[j].x), dppx<CTRL>(c[j].y));
        const float2 so = fswap(c[j]), sp = fswap(p);
        c[j] = f2fma(Bi, sp, f2fma(Br, p, f2fma(Ai, so, f2mul(Ar, c[j]))));
    }
}

__device__ __forceinline__ void loadgrp(const float* re, const float* im, int a, float2* c) {
    const float4 r = *(const float4*)&re[a];
    const float4 i = *(const float4*)&im[a];
    c[0] = make_float2(r.x, i.x); c[1] = make_float2(r.y, i.y);
    c[2] = make_float2(r.z, i.z); c[3] = make_float2(r.w, i.w);
}
__device__ __forceinline__ void storegrp(float* re, float* im, int a, const float2* c) {
    *(float4*)&re[a] = make_float4(c[0].x, c[1].x, c[2].x, c[3].x);
    *(float4*)&im[a] = make_float4(c[0].y, c[1].y, c[2].y, c[3].y);
}

__global__ __launch_bounds__(BLOCK, 4) void qsim_kernel(
    const float* __restrict__ x,
    const float* __restrict__ w,
    float* __restrict__ out)
{
    __shared__ __align__(16) float re[DIM];
    __shared__ __align__(16) float im[DIM];
    __shared__ __align__(16) float gm[NGATE * 8];
    __shared__ float red_ss[8], red_acc[8];

    const int b = blockIdx.x;
    const int t = threadIdx.x;

    // ---- gate matrices, 26 threads, once per block ----
    if (t < NGATE) {
        const float phi = w[t * 3 + 0], theta = w[t * 3 + 1], omega = w[t * 3 + 2];
        float co, si;  sincosf(0.5f * theta, &si, &co);
        float sps, cps, sds, cds;
        sincosf(0.5f * (phi + omega), &sps, &cps);
        sincosf(0.5f * (phi - omega), &sds, &cds);
        float* g = &gm[t * 8];
        g[0] =  cps * co;  g[1] = -sps * co;   // u00
        g[2] = -cds * si;  g[3] = -sds * si;   // u01
        g[4] =  cds * si;  g[5] = -sds * si;   // u10
        g[6] =  cps * co;  g[7] =  sps * co;   // u11
    }

    // ---- P0: coalesced global -> LDS (re only; state starts real), ss ----
    const float4* x4 = (const float4*)(x + (size_t)b * DIM);
    float ss = 0.f;
    #pragma unroll
    for (int k = 0; k < 4; ++k) {
        const int m = t + BLOCK * k;
        const int a = SW(4 * m);
        const float4 v = x4[m];
        *(float4*)&re[a] = v;
        ss += v.x * v.x + v.y * v.y + v.z * v.z + v.w * v.w;
    }
    #pragma unroll
    for (int off = 32; off > 0; off >>= 1) ss += __shfl_down(ss, off, 64);
    if ((t & 63) == 0) red_ss[t >> 6] = ss;
    __syncthreads();                      // B1: gm + re staging + red_ss visible
    float total = 0.f;
    #pragma unroll
    for (int i = 0; i < 8; ++i) total += red_ss[i];  // ||x||^2, invariant

    float2 c[16];

    // Per-pass (t,j)->i mappings (identical to R4; all in-place, all b128):
    //  P1: i = t<<4 | j            reg i[3:0] (q12..q9), dpp i[5:4]=t[1:0] (q8,q7)
    //  P2: i[1:0]=j[1:0], i[7:6]=j[3:2], i[5:2]=t[5:2], i[9:8]=t[1:0], i[12:10]=t[8:6]
    //      reg gates i6,i7 (q6,q5), dpp i8,i9 (q4,q3)
    //  P3: i[1:0]=j[1:0], i[11:10]=j[3:2], i[9:2]=t[8:1], i12=t[0]
    //      reg gates i10,i11 (q2,q1), dpp i12 (q0)
    const int base2 = (((t >> 2) & 15) << 2) | ((t & 3) << 8) | (((t >> 6) & 7) << 10);
    const int base3 = (((t >> 1) & 255) << 2) | ((t & 1) << 12);

    #pragma unroll
    for (int l = 0; l < 2; ++l) {
        const int G = l * 13;

        // ---- pass 1: 6 gates (q12..q7) ----
        if (l == 0) {
            // im is identically zero at entry: load re only
            #pragma unroll
            for (int g = 0; g < 4; ++g) {
                const float4 r = *(const float4*)&re[SW((t << 4) | (g << 2))];
                c[4 * g + 0] = make_float2(r.x, 0.f);
                c[4 * g + 1] = make_float2(r.y, 0.f);
                c[4 * g + 2] = make_float2(r.z, 0.f);
                c[4 * g + 3] = make_float2(r.w, 0.f);
            }
        } else {
            #pragma unroll
            for (int g = 0; g < 4; ++g)
                loadgrp(re, im, SW((t << 4) | (g << 2)), &c[4 * g]);
        }
        rotp<0>(c, ldg8(gm, G + 12));
        rotp<1>(c, ldg8(gm, G + 11));
        rotp<2>(c, ldg8(gm, G + 10));
        rotp<3>(c, ldg8(gm, G +  9));
        rotlane<0xB1>(c, ldg8(gm, G + 8), (t & 1) != 0);
        rotlane<0x4E>(c, ldg8(gm, G + 7), (t & 2) != 0);
        #pragma unroll
        for (int g = 0; g < 4; ++g)
            storegrp(re, im, SW((t << 4) | (g << 2)), &c[4 * g]);
        __syncthreads();

        // ---- pass 2: 4 gates (q6..q3) ----
        #pragma unroll
        for (int h = 0; h < 4; ++h) loadgrp(re, im, SW(base2 | (h << 6)), &c[4 * h]);
        rotp<2>(c, ldg8(gm, G + 6));
        rotp<3>(c, ldg8(gm, G + 5));
        rotlane<0xB1>(c, ldg8(gm, G + 4), (t & 1) != 0);
        rotlane<0x4E>(c, ldg8(gm, G + 3), (t & 2) != 0);
        #pragma unroll
        for (int h = 0; h < 4; ++h) storegrp(re, im, SW(base2 | (h << 6)), &c[4 * h]);
        __syncthreads();

        // ---- pass 3: 3 gates (q2,q1,q0) ----
        #pragma unroll
        for (int h = 0; h < 4; ++h) loadgrp(re, im, SW(base3 | (h << 10)), &c[4 * h]);
        if (l == 0) __syncthreads();   // reads drained before scatter (layer 0 only)
        rotp<2>(c, ldg8(gm, G + 2));
        rotp<3>(c, ldg8(gm, G + 1));
        rotlane<0xB1>(c, ldg8(gm, G + 0), (t & 1) != 0);

        if (l == 0) {
            // all 13 layer-0 CNOTs as one GF(2)-linear scatter
            int mb = 0;
            if (t & 1) mb ^= C1.c[12];
            #pragma unroll
            for (int bb = 0; bb < 8; ++bb)
                if ((t >> (bb + 1)) & 1) mb ^= C1.c[2 + bb];
            #pragma unroll
            for (int j = 0; j < 16; ++j) {
                const int a = SW(mb ^ KC.k[j]);
                re[a] = c[j].x; im[a] = c[j].y;
            }
            __syncthreads();
        }
    }

    // ---- layer-1 CNOTs + PauliZ(q6) folded: sign = popc(i & RM6) & 1 ----
    const int sbase = __popc(base3 & RM6) & 1;   // base3 == thread's fixed i-bits
    float acc = 0.f;
    #pragma unroll
    for (int j = 0; j < 16; ++j) {
        const float p = c[j].x * c[j].x + c[j].y * c[j].y;
        acc += (sbase ^ ((SJW >> j) & 1)) ? -p : p;
    }
    #pragma unroll
    for (int off = 32; off > 0; off >>= 1) acc += __shfl_down(acc, off, 64);
    if ((t & 63) == 0) red_acc[t >> 6] = acc;
    __syncthreads();
    if (t == 0) {
        float tot = 0.f;
        #pragma unroll
        for (int i = 0; i < 8; ++i) tot += red_acc[i];
        out[b] = tot / total;
    }
}

extern "C" void kernel_launch(void* const* d_in, const int* in_sizes, int n_in,
                              void* d_out, int out_size, void* d_ws, size_t ws_size,
                              hipStream_t stream) {
    const float* x = (const float*)d_in[0];   // (512, 8192) fp32
    const float* w = (const float*)d_in[1];   // (2, 13, 3) fp32
    float* out = (float*)d_out;               // (512,) fp32
    const int B = in_sizes[0] / DIM;
    qsim_kernel<<<B, BLOCK, 0, stream>>>(x, w, out);
}